// Round 5
// baseline (169.615 us; speedup 1.0000x reference)
//
#include <hip/hip_runtime.h>
#include <cstdint>
#include <cstddef>

// GPT-2 attention block, bf16 MFMA. B=2, S=2048, NX=1024, H=16, D=64.
// ws layout (48 MiB):
//   [0,8M)    xb   : x as bf16            [4096][1024]
//   [8M,14M)  wTa  : w_attn^T as bf16     [3072][1024]
//   [14M,16M) wTp  : w_proj^T as bf16     [1024][1024]
//   [16M,40M) qkv  : bf16                 [4096][3072]
//   [40M,48M) abuf : attn out bf16        [4096][1024]

typedef __bf16 bf16;
typedef __bf16 bf16x8 __attribute__((ext_vector_type(8)));
typedef __bf16 bf16x4 __attribute__((ext_vector_type(4)));
typedef float f32x4 __attribute__((ext_vector_type(4)));

#define MFMA16(a, b, c) __builtin_amdgcn_mfma_f32_16x16x32_bf16(a, b, c, 0, 0, 0)

typedef const __attribute__((address_space(1))) void* gas_ptr;
typedef __attribute__((address_space(3))) void* las_ptr;
__device__ __forceinline__ void async16(const void* g, void* l) {
    __builtin_amdgcn_global_load_lds((gas_ptr)g, (las_ptr)l, 16, 0, 0);
}
__device__ __forceinline__ float exp2f_fast(float x) { return __builtin_amdgcn_exp2f(x); }

// ---------------- fused prep: cvt x->bf16 + transpose both weights ----------------
__global__ __launch_bounds__(256) void prep_kernel(const float* __restrict__ x, bf16* __restrict__ xb,
                                                   const float* __restrict__ wa, bf16* __restrict__ wTa,
                                                   const float* __restrict__ wp, bf16* __restrict__ wTp) {
    __shared__ float tile[32][33];
    const int bid = blockIdx.x, tid = threadIdx.x;
    if (bid < 4096) {
        int i = (bid * 256 + tid) * 4;
        float4 v = *reinterpret_cast<const float4*>(x + i);
        bf16x4 o;
        o[0] = (bf16)v.x; o[1] = (bf16)v.y; o[2] = (bf16)v.z; o[3] = (bf16)v.w;
        *reinterpret_cast<bf16x4*>(xb + i) = o;
        return;
    }
    const float* in; bf16* out; int N, t;
    if (bid < 7168) { t = bid - 4096; in = wa; out = wTa; N = 3072; }
    else            { t = bid - 7168; in = wp; out = wTp; N = 1024; }
    const int K = 1024;
    int bx = t % (N >> 5), by = t / (N >> 5);
    int n0 = bx * 32, k0 = by * 32, tx = tid & 31, ty = tid >> 5;
#pragma unroll
    for (int i = 0; i < 32; i += 8)
        tile[ty + i][tx] = in[(size_t)(k0 + ty + i) * N + n0 + tx];
    __syncthreads();
#pragma unroll
    for (int i = 0; i < 32; i += 8)
        out[(size_t)(n0 + ty + i) * K + k0 + tx] = (bf16)tile[tx][ty + i];
}

// ---------------- bf16 GEMM 128x128, BK=32, dbuf, PACKED conflict-free LDS ----------------
// LDS tiles stored PACKED: logical [128 rows][32 elems] held as [64 R][8 pos]
// 16B chunks; global row gr, k-chunk kc (0..3) sits at R=gr>>1,
// pos=((gr&1)*4+kc)^(R&7). Row stride 128B (full bank wrap) + XOR => a 16-lane
// frag-read group touches each 16B position exactly 2x (2-way = free, m136),
// vs 8-way in the old 64B-row layout (3.15M conflict cycles ~= 5us measured).
// Source permutation precomputed per thread; LDS dest stays lane-linear
// (global_load_lds constraint). XCD swizzle kept (nwg%8==0).
template <int OUT_BF16>
__global__ __launch_bounds__(256) void gemm_kernel(const bf16* __restrict__ A,
                                                   const bf16* __restrict__ Bt,
                                                   const float* __restrict__ bias,
                                                   void* __restrict__ Cout,
                                                   int M, int N, int K) {
    __shared__ bf16 Alds[2][128 * 32];
    __shared__ bf16 Blds[2][128 * 32];
    const int tid = threadIdx.x;
    const int w = tid >> 6, l = tid & 63;
    const int lane16 = l & 15, quad = l >> 4;
    const int wr = w >> 1, wc = w & 1;

    const int nwg = gridDim.x * gridDim.y;
    const int lin = blockIdx.x + gridDim.x * blockIdx.y;
    const int q8 = nwg >> 3;
    const int swz = (lin & 7) * q8 + (lin >> 3);
    const int bx = swz % gridDim.x, by = swz / gridDim.x;
    const int row0 = by * 128, col0 = bx * 128;

    // staging chunk -> (global row, k-offset) map, k0-independent
    int grs[2], gks[2];
#pragma unroll
    for (int c = 0; c < 2; ++c) {
        int idx = c * 256 + tid;
        int R = idx >> 3, pos = idx & 7;
        int pos2 = pos ^ (R & 7);
        grs[c] = 2 * R + (pos2 >> 2);
        gks[c] = (pos2 & 3) * 8;
    }

    f32x4 zero4 = {0.f, 0.f, 0.f, 0.f};
    f32x4 acc[4][4];
#pragma unroll
    for (int i = 0; i < 4; ++i)
#pragma unroll
        for (int j = 0; j < 4; ++j) acc[i][j] = zero4;

    auto stage = [&](int buf, int k0) {
#pragma unroll
        for (int c = 0; c < 2; ++c) {
            int idx = c * 256 + tid;
            async16(A + (size_t)(row0 + grs[c]) * K + k0 + gks[c], &Alds[buf][idx * 8]);
            async16(Bt + (size_t)(col0 + grs[c]) * K + k0 + gks[c], &Blds[buf][idx * 8]);
        }
    };

    stage(0, 0);
    const int niter = K >> 5;
    for (int it = 0; it < niter; ++it) {
        const int cur = it & 1;
        __syncthreads();
        if (it + 1 < niter) stage(cur ^ 1, (it + 1) << 5);
        bf16x8 af[4], bfr[4];
#pragma unroll
        for (int i = 0; i < 4; ++i) {
            int gra = 64 * wr + 16 * i + lane16;
            int Ra = gra >> 1;
            int pa = ((gra & 1) * 4 + quad) ^ (Ra & 7);
            af[i] = *reinterpret_cast<const bf16x8*>(&Alds[cur][Ra * 64 + pa * 8]);
            int grb = 64 * wc + 16 * i + lane16;
            int Rb = grb >> 1;
            int pb = ((grb & 1) * 4 + quad) ^ (Rb & 7);
            bfr[i] = *reinterpret_cast<const bf16x8*>(&Blds[cur][Rb * 64 + pb * 8]);
        }
#pragma unroll
        for (int i = 0; i < 4; ++i)
#pragma unroll
            for (int j = 0; j < 4; ++j) acc[i][j] = MFMA16(af[i], bfr[j], acc[i][j]);
    }

#pragma unroll
    for (int i = 0; i < 4; ++i)
#pragma unroll
        for (int j = 0; j < 4; ++j)
#pragma unroll
            for (int r = 0; r < 4; ++r) {
                int row = row0 + 64 * wr + 16 * i + quad * 4 + r;
                int col = col0 + 64 * wc + 16 * j + lane16;
                float v = acc[i][j][r] + bias[col];
                if (OUT_BF16)
                    reinterpret_cast<bf16*>(Cout)[(size_t)row * N + col] = (bf16)v;
                else
                    reinterpret_cast<float*>(Cout)[(size_t)row * N + col] = v;
            }
}

// ---------------- bf16 GEMM 64x64, BK=64, XOR-swizzled LDS, dbuf, XCD-swizzled ----------------
// For the proj GEMM (M=4096, N=1024): the old 64x128 tile capped the grid at
// 512 blocks = 2 blocks/CU (occupancy-starved, ~290 TF). 64x64 tiles give
// grid (16,64)=1024 = 4 blocks/CU; LDS 32 KB; 128B rows + XOR-8 swizzle are
// conflict-free. Bijective XCD swizzle: per XCD 8 M-rows x all N => 1 MB A +
// 2 MB B resident in its L2.
__global__ __launch_bounds__(256) void gemm64sq_kernel(const bf16* __restrict__ A,
                                                       const bf16* __restrict__ Bt,
                                                       const float* __restrict__ bias,
                                                       float* __restrict__ Cout,
                                                       int M, int N, int K) {
    __shared__ bf16 Alds[2][64 * 64];
    __shared__ bf16 Blds[2][64 * 64];
    const int tid = threadIdx.x;
    const int w = tid >> 6, l = tid & 63;
    const int lane16 = l & 15, quad = l >> 4;
    const int wr = w >> 1, wc = w & 1;

    const int nwg = gridDim.x * gridDim.y;      // 1024, %8==0
    const int lin = blockIdx.x + gridDim.x * blockIdx.y;
    const int q8 = nwg >> 3;
    const int swz = (lin & 7) * q8 + (lin >> 3);
    const int bx = swz % gridDim.x, by = swz / gridDim.x;
    const int row0 = by * 64, col0 = bx * 64;

    f32x4 zero4 = {0.f, 0.f, 0.f, 0.f};
    f32x4 acc[2][2];
#pragma unroll
    for (int i = 0; i < 2; ++i)
#pragma unroll
        for (int j = 0; j < 2; ++j) acc[i][j] = zero4;

    auto stage = [&](int buf, int k0) {
#pragma unroll
        for (int c = 0; c < 2; ++c) {
            int idx = c * 256 + tid;
            int r = idx >> 3, cc = idx & 7, gc = cc ^ (r & 7);
            async16(A + (size_t)(row0 + r) * K + k0 + gc * 8, &Alds[buf][idx * 8]);
            async16(Bt + (size_t)(col0 + r) * K + k0 + gc * 8, &Blds[buf][idx * 8]);
        }
    };

    stage(0, 0);
    const int niter = K >> 6;   // 16
    for (int it = 0; it < niter; ++it) {
        const int cur = it & 1;
        __syncthreads();
        if (it + 1 < niter) stage(cur ^ 1, (it + 1) << 6);
        bf16x8 af[2][2], bfr[2][2];
#pragma unroll
        for (int i = 0; i < 2; ++i) {
            int r = 32 * wr + 16 * i + lane16;
#pragma unroll
            for (int ks = 0; ks < 2; ++ks) {
                int cc = (quad + 4 * ks) ^ (r & 7);
                af[i][ks] = *reinterpret_cast<const bf16x8*>(&Alds[cur][r * 64 + cc * 8]);
            }
        }
#pragma unroll
        for (int j = 0; j < 2; ++j) {
            int r = 32 * wc + 16 * j + lane16;
#pragma unroll
            for (int ks = 0; ks < 2; ++ks) {
                int cc = (quad + 4 * ks) ^ (r & 7);
                bfr[j][ks] = *reinterpret_cast<const bf16x8*>(&Blds[cur][r * 64 + cc * 8]);
            }
        }
#pragma unroll
        for (int ks = 0; ks < 2; ++ks)
#pragma unroll
            for (int i = 0; i < 2; ++i)
#pragma unroll
                for (int j = 0; j < 2; ++j) acc[i][j] = MFMA16(af[i][ks], bfr[j][ks], acc[i][j]);
    }

#pragma unroll
    for (int i = 0; i < 2; ++i)
#pragma unroll
        for (int j = 0; j < 2; ++j)
#pragma unroll
            for (int r = 0; r < 4; ++r) {
                int row = row0 + 32 * wr + 16 * i + quad * 4 + r;
                int col = col0 + 32 * wc + 16 * j + lane16;
                Cout[(size_t)row * N + col] = acc[i][j][r] + bias[col];
            }
}

// ---------------- flash attention: 64 q-rows/block, dbuf K/V, XOR-swizzled LDS ----------------
// R3 structure (dbuf, 1 barrier/tile, swizzled LDS) + T5 s_setprio around both
// MFMA clusters (R4). Unchanged this round.
__global__ __launch_bounds__(256) void attn_kernel(const bf16* __restrict__ qkv,
                                                   bf16* __restrict__ aout) {
    const int S = 2048;
    const int bh = blockIdx.x;
    const int b = bh >> 4, hd = bh & 15;
    const int rr = blockIdx.y >> 3, j = blockIdx.y & 7;
    const int qt = (rr == 0) ? (31 - j) : (rr == 1) ? (16 + j) : (rr == 2) ? (15 - j) : j;
    const int nkt = qt + 1;
    const int tid = threadIdx.x, w = tid >> 6, l = tid & 63;
    const int lane16 = l & 15, quad = l >> 4;

    __shared__ bf16 Klds[2][64 * 64];   // [k][d], swizzled
    __shared__ bf16 Vt[2][64 * 64];     // [d][k], swizzled
    __shared__ bf16 Plds[4][16 * 64];   // per-wave private, swizzled

    const bf16* base = qkv + (size_t)b * S * 3072;
    const float qscale = 0.125f * 1.4426950408889634f;
    const float NEGs = -10000.0f * 1.4426950408889634f;

    bf16x8 qf[2];
#pragma unroll
    for (int hv = 0; hv < 2; ++hv) {
        const bf16* qp = base + (size_t)(qt * 64 + 16 * w + lane16) * 3072 + hd * 64;
        bf16x8 t = *reinterpret_cast<const bf16x8*>(qp + hv * 32 + quad * 8);
#pragma unroll
        for (int jj = 0; jj < 8; ++jj) t[jj] = (bf16)((float)t[jj] * qscale);
        qf[hv] = t;
    }

    f32x4 zero4 = {0.f, 0.f, 0.f, 0.f};
    f32x4 o[4];
#pragma unroll
    for (int df = 0; df < 4; ++df) o[df] = zero4;
    float lsum = 0.f;

    const int kr = tid >> 3, kcc = tid & 7;
    const int vp = tid & 31, vd = (tid >> 5) * 8;
    bf16x8 kreg0, kreg1, vreg0, vreg1;
    auto load_tile = [&](int kt) {
        const bf16* tb = base + (size_t)(kt * 64) * 3072;
        kreg0 = *reinterpret_cast<const bf16x8*>(tb + (size_t)kr * 3072 + 1024 + hd * 64 + kcc * 8);
        kreg1 = *reinterpret_cast<const bf16x8*>(tb + (size_t)(32 + kr) * 3072 + 1024 + hd * 64 + kcc * 8);
        vreg0 = *reinterpret_cast<const bf16x8*>(tb + (size_t)(2 * vp) * 3072 + 2048 + hd * 64 + vd);
        vreg1 = *reinterpret_cast<const bf16x8*>(tb + (size_t)(2 * vp + 1) * 3072 + 2048 + hd * 64 + vd);
    };
    auto write_KV = [&](int buf) {
        bf16* Kb = &Klds[buf][0];
        bf16* Vb = &Vt[buf][0];
        const int kchunk = kcc ^ (kr & 7);
        *reinterpret_cast<bf16x8*>(&Kb[kr * 64 + kchunk * 8]) = kreg0;
        *reinterpret_cast<bf16x8*>(&Kb[(32 + kr) * 64 + kchunk * 8]) = kreg1;
#pragma unroll
        for (int jj = 0; jj < 8; ++jj) {
            int row = vd + jj;
            union { bf16 h2v[2]; uint32_t u; } pk;
            pk.h2v[0] = vreg0[jj]; pk.h2v[1] = vreg1[jj];
            int idx = row * 64 + (((vp >> 2) ^ (row & 7)) * 8) + (vp & 3) * 2;
            *reinterpret_cast<uint32_t*>(&Vb[idx]) = pk.u;
        }
    };

    load_tile(0);
    write_KV(0);
    if (nkt > 1) load_tile(1);
    __syncthreads();

    for (int kt = 0; kt < nkt; ++kt) {
        const int p = kt & 1;
        if (kt + 1 < nkt) write_KV(p ^ 1);

        const bf16* Kb = &Klds[p][0];
        const bf16* Vb = &Vt[p][0];

        __builtin_amdgcn_s_setprio(1);
        f32x4 st[4];
#pragma unroll
        for (int kf = 0; kf < 4; ++kf) {
            int row = kf * 16 + lane16;
            int c0 = quad ^ (row & 7);
            int c1 = (4 + quad) ^ (row & 7);
            bf16x8 k0 = *reinterpret_cast<const bf16x8*>(&Kb[row * 64 + c0 * 8]);
            bf16x8 k1 = *reinterpret_cast<const bf16x8*>(&Kb[row * 64 + c1 * 8]);
            f32x4 z = zero4;
            z = MFMA16(k0, qf[0], z);
            z = MFMA16(k1, qf[1], z);
            st[kf] = z;
        }
        __builtin_amdgcn_s_setprio(0);

        if (kt + 2 < nkt) load_tile(kt + 2);

        if (kt == qt) {
            const int q = qt * 64 + 16 * w + lane16;
#pragma unroll
            for (int kf = 0; kf < 4; ++kf)
#pragma unroll
                for (int r = 0; r < 4; ++r)
                    if (kt * 64 + kf * 16 + quad * 4 + r > q) st[kf][r] = NEGs;
        }

        float rs = 0.f;
        bf16* Prow = &Plds[w][lane16 * 64];
        const int rx = lane16 & 7;
#pragma unroll
        for (int kf = 0; kf < 4; ++kf) {
            bf16x4 pk;
#pragma unroll
            for (int r = 0; r < 4; ++r) {
                float pv = exp2f_fast(st[kf][r]);
                rs += pv;
                pk[r] = (bf16)pv;
            }
            int chunk = (2 * kf + (quad >> 1)) ^ rx;
            *reinterpret_cast<bf16x4*>(Prow + chunk * 8 + (quad & 1) * 4) = pk;
        }
        lsum += rs;

        __builtin_amdgcn_s_setprio(1);
#pragma unroll
        for (int kf2 = 0; kf2 < 2; ++kf2) {
            int pc = (kf2 * 4 + quad) ^ rx;
            bf16x8 pf = *reinterpret_cast<const bf16x8*>(&Plds[w][lane16 * 64 + pc * 8]);
#pragma unroll
            for (int df = 0; df < 4; ++df) {
                int vrow = df * 16 + lane16;
                int vc = (kf2 * 4 + quad) ^ (vrow & 7);
                bf16x8 vf = *reinterpret_cast<const bf16x8*>(&Vb[vrow * 64 + vc * 8]);
                o[df] = MFMA16(pf, vf, o[df]);
            }
        }
        __builtin_amdgcn_s_setprio(0);

        __syncthreads();
    }

    lsum += __shfl_xor(lsum, 16, 64);
    lsum += __shfl_xor(lsum, 32, 64);
    float inv = 1.0f / lsum;

#pragma unroll
    for (int r = 0; r < 4; ++r) {
        float li = __shfl(inv, quad * 4 + r, 64);
        int row = qt * 64 + 16 * w + quad * 4 + r;
#pragma unroll
        for (int df = 0; df < 4; ++df)
            aout[(size_t)(b * S + row) * 1024 + hd * 64 + df * 16 + lane16] =
                (bf16)(o[df][r] * li);
    }
}

extern "C" void kernel_launch(void* const* d_in, const int* in_sizes, int n_in,
                              void* d_out, int out_size, void* d_ws, size_t ws_size,
                              hipStream_t stream) {
    const float* x      = (const float*)d_in[0];
    const float* w_attn = (const float*)d_in[1];
    const float* b_attn = (const float*)d_in[2];
    const float* w_proj = (const float*)d_in[3];
    const float* b_proj = (const float*)d_in[4];
    float* out = (float*)d_out;
    char* ws = (char*)d_ws;

    const int Mtok = 4096, NX = 1024, N3 = 3072;
    bf16* xb   = (bf16*)(ws);
    bf16* wTa  = (bf16*)(ws + ((size_t)8 << 20));
    bf16* wTp  = (bf16*)(ws + ((size_t)14 << 20));
    bf16* qkv  = (bf16*)(ws + ((size_t)16 << 20));
    bf16* abuf = (bf16*)(ws + ((size_t)40 << 20));

    prep_kernel<<<dim3(8192), 256, 0, stream>>>(x, xb, w_attn, wTa, w_proj, wTp);
    gemm_kernel<1><<<dim3(N3 / 128, Mtok / 128), 256, 0, stream>>>(xb, wTa, b_attn, qkv, Mtok, N3, NX);
    attn_kernel<<<dim3(32, 32), 256, 0, stream>>>(qkv, abuf);
    gemm64sq_kernel<<<dim3(NX / 64, Mtok / 64), 256, 0, stream>>>(abuf, wTp, b_proj, out, Mtok, NX, NX);
}